// Round 16
// baseline (67.588 us; speedup 1.0000x reference)
//
#include <hip/hip_runtime.h>
#include <cstdint>
#include <cstddef>

// Fused prefix-LM self-attention, B=8192, S=64, D=32, H=4, DH=8.
// Block = 128 thr = 2 waves; 4 batches/block (grid 2048), weights hoisted.
// bf16 MFMA 16x16x32 end-to-end; sigma-permuted V^T so P feeds PV directly
// from registers; ones-row colsum; concat-head full-K tail projection.
// R16: prefix-LM mask folded into the S-MFMA C-OPERAND: sacc starts at
// M in {0,-100} instead of 0, exp2 runs unconditionally (exp2(s-100)~1e-29
// ~ 0 at bf16 precision). jb is the outer loop so M[it] (built once per
// jb, 128 instr/wave) is shared by BOTH heads -> deletes the 256/wave
// post-exp cmp+cndmask chain (~14% of VALU issue).
#define NB 8192
#define NBPB 4

typedef __attribute__((ext_vector_type(8))) short short8;
typedef __attribute__((ext_vector_type(4))) float f32x4;

union S8U { short8 s; unsigned u[4]; uint4 v; };
union FI { float f; int i; unsigned u; };

static __device__ __forceinline__ unsigned pk2(float a, float b) {
    unsigned short ua = __builtin_bit_cast(unsigned short, (__bf16)a);
    unsigned short ub = __builtin_bit_cast(unsigned short, (__bf16)b);
    return (unsigned)ua | ((unsigned)ub << 16);
}

#define MFMA __builtin_amdgcn_mfma_f32_16x16x32_bf16
#define BPERM __builtin_amdgcn_ds_bpermute

__global__ __launch_bounds__(128) void fused_attn_mfma(
    const float* __restrict__ x,
    const int*   __restrict__ aatt,
    const float* __restrict__ Wq, const float* __restrict__ bq,
    const float* __restrict__ Wk, const float* __restrict__ bk,
    const float* __restrict__ Wv, const float* __restrict__ bv,
    const float* __restrict__ Wp, const float* __restrict__ bp,
    float* __restrict__ out)
{
    __shared__ __align__(16) short klds[64][40];   // K[seq][dim]; tail: O[i][dim]
    __shared__ __align__(16) short vbt[33][72];    // V^T[dim][sigma(j)] + ones row

    const int tid  = threadIdx.x;
    const int w    = tid >> 6;          // wave: heads {2w, 2w+1}, dims 16w..16w+15
    const int lane = tid & 63;
    const int q4   = lane >> 4;
    const int l15  = lane & 15;

    const unsigned bmask = (q4 == 0) ? 0xFFFFFFFFu : 0u;

    auto wrow = [&](const float* W, int row) -> short8 {
        const float* p = W + row*32 + q4*8;
        float4 u0 = *(const float4*)p;
        float4 u1 = *(const float4*)(p + 4);
        S8U t;
        t.u[0] = pk2(u0.x, u0.y); t.u[1] = pk2(u0.z, u0.w);
        t.u[2] = pk2(u1.x, u1.y); t.u[3] = pk2(u1.z, u1.w);
        return t.s;
    };

    const float escale = 0.35355339059327373f * 1.4426950408889634f; // 1/sqrt(8)*log2(e)

    // ---- hoisted per-block state ----
    const short8 wq8 = wrow(Wq, 16*w + l15);
    const short8 wk8 = wrow(Wk, 16*w + l15);
    const short8 wv8 = wrow(Wv, 16*w + l15);
    const float4 bq4 = *(const float4*)(bq + 16*w + q4*4);
    const float4 bk4 = *(const float4*)(bk + 16*w + q4*4);
    const float  bvv = bv[16*w + l15];
    short8 wpb[2];
    wpb[0] = wrow(Wp, l15);
    wpb[1] = wrow(Wp, 16 + l15);
    const float bpv[2] = { bp[l15], bp[16 + l15] };

    if (q4 == 0) {   // ones row 32 (V staging never touches row 32)
        uint2 ones; ones.x = 0x3F803F80u; ones.y = 0x3F803F80u;
        *(uint2*)&vbt[32][l15*4] = ones;
    }

#pragma unroll 1
    for (int bi = 0; bi < NBPB; ++bi) {
        const int b = blockIdx.x * NBPB + bi;
        const int aab = aatt[b];

        // allowed(j) == j <= max(i, aab-1); j = (compile-time C) + q4*4
        int cmpv[4];
#pragma unroll
        for (int it = 0; it < 4; ++it) cmpv[it] = max(l15 + 16*it, aab - 1) - q4*4;

        // ---- X fragments ----
        short8 xa[4];
        const float* xb = x + (size_t)b * 64 * 32;
#pragma unroll
        for (int nt = 0; nt < 4; ++nt) {
            const float* p = xb + (nt*16 + l15)*32 + q4*8;
            float4 u0 = *(const float4*)p;
            float4 u1 = *(const float4*)(p + 4);
            S8U t;
            t.u[0] = pk2(u0.x, u0.y); t.u[1] = pk2(u0.z, u0.w);
            t.u[2] = pk2(u1.x, u1.y); t.u[3] = pk2(u1.z, u1.w);
            xa[nt] = t.s;
        }

        // ---- Q^T -> registers (packed, pre-scaled) ----
        unsigned qpk01[4], qpk23[4];
#pragma unroll
        for (int nt = 0; nt < 4; ++nt) {
            f32x4 acc = {0.f,0.f,0.f,0.f};
            acc = MFMA(wq8, xa[nt], acc, 0,0,0);
            qpk01[nt] = pk2((acc[0]+bq4.x)*escale, (acc[1]+bq4.y)*escale);
            qpk23[nt] = pk2((acc[2]+bq4.z)*escale, (acc[3]+bq4.w)*escale);
        }
        // ---- K^T -> klds cols 16w.. ----
#pragma unroll
        for (int nt = 0; nt < 4; ++nt) {
            f32x4 acc = {0.f,0.f,0.f,0.f};
            acc = MFMA(wk8, xa[nt], acc, 0,0,0);
            uint2 w2;
            w2.x = pk2(acc[0]+bk4.x, acc[1]+bk4.y);
            w2.y = pk2(acc[2]+bk4.z, acc[3]+bk4.w);
            *(uint2*)&klds[nt*16 + l15][16*w + q4*4] = w2;
        }
        // ---- V -> vbt rows 16w.. sigma-permuted ----
#pragma unroll
        for (int mt = 0; mt < 4; ++mt) {
            f32x4 acc = {0.f,0.f,0.f,0.f};
            acc = MFMA(xa[mt], wv8, acc, 0,0,0);
            uint2 w2;
            w2.x = pk2(acc[0]+bvv, acc[1]+bvv);
            w2.y = pk2(acc[2]+bvv, acc[3]+bvv);
            *(uint2*)&vbt[16*w + l15][(mt >> 1)*32 + q4*8 + (mt & 1)*4] = w2;
        }

        // ---- Q B-frags for both heads (qpk dead after) ----
        short8 sqb[2][4];
#pragma unroll
        for (int hl = 0; hl < 2; ++hl) {
            const int idxA = (32*hl + l15) * 4;
            const int idxB = idxA + 64;
#pragma unroll
            for (int it = 0; it < 4; ++it) {
                S8U t;
                t.u[0] = (unsigned)BPERM(idxA, (int)qpk01[it]) & bmask;
                t.u[1] = (unsigned)BPERM(idxA, (int)qpk23[it]) & bmask;
                t.u[2] = (unsigned)BPERM(idxB, (int)qpk01[it]) & bmask;
                t.u[3] = (unsigned)BPERM(idxB, (int)qpk23[it]) & bmask;
                sqb[hl][it] = t.s;
            }
        }

        f32x4 oacc[2][4];
#pragma unroll
        for (int hl = 0; hl < 2; ++hl)
#pragma unroll
            for (int it = 0; it < 4; ++it) oacc[hl][it] = (f32x4){0.f,0.f,0.f,0.f};

        // ---- jb-outer: M shared across both heads ----
#pragma unroll
        for (int jb = 0; jb < 2; ++jb) {
            // mask-as-C-init: M = 0 (allowed) / -100 (masked)
            f32x4 Mlo[4], Mhi[4];
#pragma unroll
            for (int it = 0; it < 4; ++it) {
#pragma unroll
                for (int r = 0; r < 4; ++r) {
                    Mlo[it][r] = (jb*32 + r      <= cmpv[it]) ? 0.0f : -100.0f;
                    Mhi[it][r] = (jb*32 + 16 + r <= cmpv[it]) ? 0.0f : -100.0f;
                }
            }
#pragma unroll
            for (int hl = 0; hl < 2; ++hl) {
                S8U ska0, ska1, av;
                ska0.v = *(const uint4*)&klds[jb*32 + l15][16*w + 8*hl];
                ska1.v = *(const uint4*)&klds[jb*32 + 16 + l15][16*w + 8*hl];
                const int avrow = (l15 < 8) ? (16*w + 8*hl + l15) : 32;
                av.v = *(const uint4*)&vbt[avrow][jb*32 + q4*8];

#pragma unroll
                for (int it = 0; it < 4; ++it) {
                    f32x4 sacc0 = MFMA(ska0.s, sqb[hl][it], Mlo[it], 0,0,0);
                    f32x4 sacc1 = MFMA(ska1.s, sqb[hl][it], Mhi[it], 0,0,0);
                    S8U pb;
                    pb.u[0] = pk2(__builtin_amdgcn_exp2f(sacc0[0]),
                                  __builtin_amdgcn_exp2f(sacc0[1]));
                    pb.u[1] = pk2(__builtin_amdgcn_exp2f(sacc0[2]),
                                  __builtin_amdgcn_exp2f(sacc0[3]));
                    pb.u[2] = pk2(__builtin_amdgcn_exp2f(sacc1[0]),
                                  __builtin_amdgcn_exp2f(sacc1[1]));
                    pb.u[3] = pk2(__builtin_amdgcn_exp2f(sacc1[2]),
                                  __builtin_amdgcn_exp2f(sacc1[3]));
                    oacc[hl][it] = MFMA(av.s, pb.s, oacc[hl][it], 0,0,0);
                }
            }
        }

        // ---- normalize + O-frag stores (after all own ska reads) ----
#pragma unroll
        for (int hl = 0; hl < 2; ++hl) {
#pragma unroll
            for (int it = 0; it < 4; ++it) {
                FI s; s.i = BPERM((32 + l15) * 4,
                                  __builtin_bit_cast(int, oacc[hl][it][0]));
                const float inv = __builtin_amdgcn_rcpf(s.f);
                const unsigned o01 = pk2(oacc[hl][it][0]*inv, oacc[hl][it][1]*inv);
                const unsigned o23 = pk2(oacc[hl][it][2]*inv, oacc[hl][it][3]*inv);
                if (q4 < 2) {
                    uint2 ow; ow.x = o01; ow.y = o23;
                    *(uint2*)&klds[it*16 + l15][(2*w + hl)*8 + q4*4] = ow;
                }
            }
        }

        // ---- tail: concat-head full-K out-projection ----
        __syncthreads();   // other wave's O-cols must be visible

        float* ob = out + (size_t)b * 64 * 32;
#pragma unroll
        for (int u = 0; u < 2; ++u) {       // this wave's i-tiles: 2w, 2w+1
            S8U oa; oa.v = *(const uint4*)&klds[(2*w + u)*16 + l15][q4*8];
#pragma unroll
            for (int nt = 0; nt < 2; ++nt) {
                f32x4 y = {0.f,0.f,0.f,0.f};
                y = MFMA(oa.s, wpb[nt], y, 0,0,0);
#pragma unroll
                for (int r = 0; r < 4; ++r)
                    ob[((2*w + u)*16 + q4*4 + r)*32 + nt*16 + l15] = y[r] + bpv[nt];
            }
        }

        __syncthreads();   // klds/vbt reuse by next batch's staging
    }
}

extern "C" void kernel_launch(void* const* d_in, const int* in_sizes, int n_in,
                              void* d_out, int out_size, void* d_ws, size_t ws_size,
                              hipStream_t stream) {
    const float* x  = (const float*)d_in[0];
    const int*   aa = (const int*)d_in[1];
    const float* Wq = (const float*)d_in[2];
    const float* bq = (const float*)d_in[3];
    const float* Wk = (const float*)d_in[4];
    const float* bk = (const float*)d_in[5];
    const float* Wv = (const float*)d_in[6];
    const float* bv = (const float*)d_in[7];
    const float* Wp = (const float*)d_in[8];
    const float* bp = (const float*)d_in[9];
    float* out = (float*)d_out;

    dim3 grid(NB / NBPB), block(128);
    hipLaunchKernelGGL(fused_attn_mfma, grid, block, 0, stream,
                       x, aa, Wq, bq, Wk, bk, Wv, bv, Wp, bp, out);
}

// Round 17
// 57.508 us; speedup vs baseline: 1.1753x; 1.1753x over previous
//
#include <hip/hip_runtime.h>
#include <cstdint>
#include <cstddef>

// Fused prefix-LM self-attention, B=8192, S=64, D=32, H=4, DH=8.
// R17: 1 WAVE = 1 BATCH (block = 64 thr, grid 8192). Each wave does all
// 4 heads -> ZERO barriers, x loaded once per batch, fully independent
// per-wave instruction streams. Math identical to R14: bf16 MFMA
// 16x16x32 end-to-end; sigma-permuted V^T so P feeds PV directly from
// registers; ones-row colsum; concat-head full-K tail projection (own
// wave stages all 32 O-dims -> in-order DS, no sync).
// klds aliasing: head h reads K-cols 8h..8h+7 then O-stores the same
// cols; later heads read higher cols only -> safe per in-order DS.
#define NB 8192

typedef __attribute__((ext_vector_type(8))) short short8;
typedef __attribute__((ext_vector_type(4))) float f32x4;

union S8U { short8 s; unsigned u[4]; uint4 v; };
union FI { float f; int i; unsigned u; };

static __device__ __forceinline__ unsigned pk2(float a, float b) {
    unsigned short ua = __builtin_bit_cast(unsigned short, (__bf16)a);
    unsigned short ub = __builtin_bit_cast(unsigned short, (__bf16)b);
    return (unsigned)ua | ((unsigned)ub << 16);
}

#define MFMA __builtin_amdgcn_mfma_f32_16x16x32_bf16
#define BPERM __builtin_amdgcn_ds_bpermute

__global__ __launch_bounds__(64) void fused_attn_mfma(
    const float* __restrict__ x,
    const int*   __restrict__ aatt,
    const float* __restrict__ Wq, const float* __restrict__ bq,
    const float* __restrict__ Wk, const float* __restrict__ bk,
    const float* __restrict__ Wv, const float* __restrict__ bv,
    const float* __restrict__ Wp, const float* __restrict__ bp,
    float* __restrict__ out)
{
    __shared__ __align__(16) short klds[64][40];   // K[seq][dim]; later O[i][dim]
    __shared__ __align__(16) short vbt[33][72];    // V^T[dim][sigma(j)] + ones row

    const int lane = threadIdx.x;      // 64 threads = 1 wave = 1 batch
    const int q4   = lane >> 4;
    const int l15  = lane & 15;
    const int b    = blockIdx.x;

    const int aab = aatt[b];
    const unsigned bmask = (q4 == 0) ? 0xFFFFFFFFu : 0u;

    // allowed(j) == j <= max(i, aab-1); j = (compile-time C) + q4*4
    int cmpv[4];
#pragma unroll
    for (int it = 0; it < 4; ++it) cmpv[it] = max(l15 + 16*it, aab - 1) - q4*4;

    // ---- X fragments: row = tile*16+l15, k = q4*8+e ----
    short8 xa[4];
    const float* xb = x + (size_t)b * 64 * 32;
#pragma unroll
    for (int nt = 0; nt < 4; ++nt) {
        const float* p = xb + (nt*16 + l15)*32 + q4*8;
        float4 u0 = *(const float4*)p;
        float4 u1 = *(const float4*)(p + 4);
        S8U t;
        t.u[0] = pk2(u0.x, u0.y); t.u[1] = pk2(u0.z, u0.w);
        t.u[2] = pk2(u1.x, u1.y); t.u[3] = pk2(u1.z, u1.w);
        xa[nt] = t.s;
    }

    auto wrow = [&](const float* W, int row) -> short8 {
        const float* p = W + row*32 + q4*8;
        float4 u0 = *(const float4*)p;
        float4 u1 = *(const float4*)(p + 4);
        S8U t;
        t.u[0] = pk2(u0.x, u0.y); t.u[1] = pk2(u0.z, u0.w);
        t.u[2] = pk2(u1.x, u1.y); t.u[3] = pk2(u1.z, u1.w);
        return t.s;
    };

    const float escale = 0.35355339059327373f * 1.4426950408889634f; // 1/sqrt(8)*log2(e)

    // ---- Q^T (all 32 dims) -> registers, bias+scale in f32 ----
    unsigned qpk01[2][4], qpk23[2][4];
#pragma unroll
    for (int mt = 0; mt < 2; ++mt) {
        short8 wa = wrow(Wq, mt*16 + l15);
        float4 b4 = *(const float4*)(bq + mt*16 + q4*4);
#pragma unroll
        for (int nt = 0; nt < 4; ++nt) {
            f32x4 acc = {0.f,0.f,0.f,0.f};
            acc = MFMA(wa, xa[nt], acc, 0,0,0);
            qpk01[mt][nt] = pk2((acc[0]+b4.x)*escale, (acc[1]+b4.y)*escale);
            qpk23[mt][nt] = pk2((acc[2]+b4.z)*escale, (acc[3]+b4.w)*escale);
        }
    }
    // ---- K^T (all 32 dims) -> klds ----
#pragma unroll
    for (int mt = 0; mt < 2; ++mt) {
        short8 wa = wrow(Wk, mt*16 + l15);
        float4 b4 = *(const float4*)(bk + mt*16 + q4*4);
#pragma unroll
        for (int nt = 0; nt < 4; ++nt) {
            f32x4 acc = {0.f,0.f,0.f,0.f};
            acc = MFMA(wa, xa[nt], acc, 0,0,0);
            uint2 w2;
            w2.x = pk2(acc[0]+b4.x, acc[1]+b4.y);
            w2.y = pk2(acc[2]+b4.z, acc[3]+b4.w);
            *(uint2*)&klds[nt*16 + l15][mt*16 + q4*4] = w2;
        }
    }
    // ---- V (all 32 dims) -> vbt rows, sigma-permuted columns:
    // j = mt*16+q4*4+r  ->  p = (mt>>1)*32 + q4*8 + (mt&1)*4 + r ----
#pragma unroll
    for (int nt = 0; nt < 2; ++nt) {
        short8 wv = wrow(Wv, nt*16 + l15);
        const float bvv = bv[nt*16 + l15];
#pragma unroll
        for (int mt = 0; mt < 4; ++mt) {
            f32x4 acc = {0.f,0.f,0.f,0.f};
            acc = MFMA(xa[mt], wv, acc, 0,0,0);
            uint2 w2;
            w2.x = pk2(acc[0]+bvv, acc[1]+bvv);
            w2.y = pk2(acc[2]+bvv, acc[3]+bvv);
            *(uint2*)&vbt[nt*16 + l15][(mt >> 1)*32 + q4*8 + (mt & 1)*4] = w2;
        }
    }
    // ones row 32 (V staging never touches row 32)
    if (q4 == 0) {
        uint2 ones; ones.x = 0x3F803F80u; ones.y = 0x3F803F80u;
        *(uint2*)&vbt[32][l15*4] = ones;
    }

    // ---- head loop: all 4 heads in this wave; P stays in registers ----
#pragma unroll
    for (int h = 0; h < 4; ++h) {
        const int mth = h >> 1;            // qpk tile
        const int p   = h & 1;             // k-offset within tile (8p)
        const int idxA = (32*p + l15) * 4;
        const int idxB = idxA + 64;

        // Q B-frags: zero k>=8 via bmask
        short8 sqb[4];
#pragma unroll
        for (int it = 0; it < 4; ++it) {
            S8U t;
            t.u[0] = (unsigned)BPERM(idxA, (int)qpk01[mth][it]) & bmask;
            t.u[1] = (unsigned)BPERM(idxA, (int)qpk23[mth][it]) & bmask;
            t.u[2] = (unsigned)BPERM(idxB, (int)qpk01[mth][it]) & bmask;
            t.u[3] = (unsigned)BPERM(idxB, (int)qpk23[mth][it]) & bmask;
            sqb[it] = t.s;
        }

        // V^T A-frag rows: dims 8h.. for l15<8, ones row (colsum) for l15>=8
        const int avrow = (l15 < 8) ? (8*h + l15) : 32;

        f32x4 oacch[4];
#pragma unroll
        for (int it = 0; it < 4; ++it) oacch[it] = (f32x4){0.f,0.f,0.f,0.f};

#pragma unroll
        for (int jb = 0; jb < 2; ++jb) {
            S8U ska0, ska1, av;
            ska0.v = *(const uint4*)&klds[jb*32 + l15][8*h];
            ska1.v = *(const uint4*)&klds[jb*32 + 16 + l15][8*h];
            av.v   = *(const uint4*)&vbt[avrow][jb*32 + q4*8];

#pragma unroll
            for (int it = 0; it < 4; ++it) {
                S8U pb;
                {   // jt = 0: P j-slots q4*4..+3 -> pb dwords 0,1
                    f32x4 sacc = {0.f,0.f,0.f,0.f};
                    sacc = MFMA(ska0.s, sqb[it], sacc, 0,0,0);
                    float e[4];
#pragma unroll
                    for (int r = 0; r < 4; ++r) {
                        float ee = __builtin_amdgcn_exp2f(sacc[r]);
                        e[r] = (jb*32 + r <= cmpv[it]) ? ee : 0.0f;
                    }
                    pb.u[0] = pk2(e[0], e[1]); pb.u[1] = pk2(e[2], e[3]);
                }
                {   // jt = 1: P j-slots 16+q4*4..+3 -> pb dwords 2,3
                    f32x4 sacc = {0.f,0.f,0.f,0.f};
                    sacc = MFMA(ska1.s, sqb[it], sacc, 0,0,0);
                    float e[4];
#pragma unroll
                    for (int r = 0; r < 4; ++r) {
                        float ee = __builtin_amdgcn_exp2f(sacc[r]);
                        e[r] = (jb*32 + 16 + r <= cmpv[it]) ? ee : 0.0f;
                    }
                    pb.u[2] = pk2(e[0], e[1]); pb.u[3] = pk2(e[2], e[3]);
                }
                oacch[it] = MFMA(av.s, pb.s, oacch[it], 0,0,0);
            }
        }

        // colsum arrived in C-row 8 (lane 32+l15, reg 0) via the ones row;
        // normalize and store O-frags to klds cols 8h..8h+7 (just-read cols)
#pragma unroll
        for (int it = 0; it < 4; ++it) {
            FI s; s.i = BPERM((32 + l15) * 4, __builtin_bit_cast(int, oacch[it][0]));
            const float inv = __builtin_amdgcn_rcpf(s.f);
            const unsigned o01 = pk2(oacch[it][0]*inv, oacch[it][1]*inv);
            const unsigned o23 = pk2(oacch[it][2]*inv, oacch[it][3]*inv);
            if (q4 < 2) {
                uint2 ow; ow.x = o01; ow.y = o23;
                *(uint2*)&klds[it*16 + l15][8*h + q4*4] = ow;
            }
        }
    }

    // ---- tail: concat-head full-K out-projection (no barrier: own LDS) ----
    short8 wpb[2];
    wpb[0] = wrow(Wp, l15);
    wpb[1] = wrow(Wp, 16 + l15);
    const float bpv[2] = { bp[l15], bp[16 + l15] };

    float* ob = out + (size_t)b * 64 * 32;
#pragma unroll
    for (int it = 0; it < 4; ++it) {
        S8U oa; oa.v = *(const uint4*)&klds[it*16 + l15][q4*8];
#pragma unroll
        for (int nt = 0; nt < 2; ++nt) {
            f32x4 y = {0.f,0.f,0.f,0.f};
            y = MFMA(oa.s, wpb[nt], y, 0,0,0);
#pragma unroll
            for (int r = 0; r < 4; ++r)
                ob[(it*16 + q4*4 + r)*32 + nt*16 + l15] = y[r] + bpv[nt];
        }
    }
}

extern "C" void kernel_launch(void* const* d_in, const int* in_sizes, int n_in,
                              void* d_out, int out_size, void* d_ws, size_t ws_size,
                              hipStream_t stream) {
    const float* x  = (const float*)d_in[0];
    const int*   aa = (const int*)d_in[1];
    const float* Wq = (const float*)d_in[2];
    const float* bq = (const float*)d_in[3];
    const float* Wk = (const float*)d_in[4];
    const float* bk = (const float*)d_in[5];
    const float* Wv = (const float*)d_in[6];
    const float* bv = (const float*)d_in[7];
    const float* Wp = (const float*)d_in[8];
    const float* bp = (const float*)d_in[9];
    float* out = (float*)d_out;

    dim3 grid(NB), block(64);
    hipLaunchKernelGGL(fused_attn_mfma, grid, block, 0, stream,
                       x, aa, Wq, bq, Wk, bk, Wv, bv, Wp, bp, out);
}

// Round 18
// 53.630 us; speedup vs baseline: 1.2603x; 1.0723x over previous
//
#include <hip/hip_runtime.h>
#include <cstdint>
#include <cstddef>

// Fused prefix-LM self-attention, B=8192, S=64, D=32, H=4, DH=8.
// Block = 128 thr = 2 waves; 4 batches/block (grid 2048); weights/biases/
// fills hoisted. bf16 MFMA 16x16x32 end-to-end; sigma-permuted V^T (P
// feeds PV from registers); ones-row colsum; concat-head full-K tail.
// R18 (bpermute-ectomy): Q^T staged to qlds (wave-own cols) -> each S
// B-frag is ONE broadcast ds_read_b128 (k>=8 = harmless duplicates);
// the old B-side zero-masking moves to the A side: klds has 8 ZERO
// columns (48..55, filled once, never overwritten -- O goes to qlds);
// q4>=1 lanes read their A-frag from the zero cols (1 cndmask/head).
// Deletes 32 ds_bpermute + 64 v_and per wave/batch.
#define NB 8192
#define NBPB 4

typedef __attribute__((ext_vector_type(8))) short short8;
typedef __attribute__((ext_vector_type(4))) float f32x4;

union S8U { short8 s; unsigned u[4]; uint4 v; };
union FI { float f; int i; unsigned u; };

static __device__ __forceinline__ unsigned pk2(float a, float b) {
    unsigned short ua = __builtin_bit_cast(unsigned short, (__bf16)a);
    unsigned short ub = __builtin_bit_cast(unsigned short, (__bf16)b);
    return (unsigned)ua | ((unsigned)ub << 16);
}

#define MFMA __builtin_amdgcn_mfma_f32_16x16x32_bf16
#define BPERM __builtin_amdgcn_ds_bpermute

__global__ __launch_bounds__(128) void fused_attn_mfma(
    const float* __restrict__ x,
    const int*   __restrict__ aatt,
    const float* __restrict__ Wq, const float* __restrict__ bq,
    const float* __restrict__ Wk, const float* __restrict__ bk,
    const float* __restrict__ Wv, const float* __restrict__ bv,
    const float* __restrict__ Wp, const float* __restrict__ bp,
    float* __restrict__ out)
{
    __shared__ __align__(16) short qlds[64][40];   // Q^T[seq][dim]; tail: O[i][dim]
    __shared__ __align__(16) short klds[64][56];   // K[seq][dim0..31]; cols 48..55 = 0
    __shared__ __align__(16) short vbt[33][72];    // V^T[dim][sigma(j)] + ones row

    const int tid  = threadIdx.x;
    const int w    = tid >> 6;          // wave: heads {2w, 2w+1}, dims 16w..16w+15
    const int lane = tid & 63;
    const int q4   = lane >> 4;
    const int l15  = lane & 15;

    auto wrow = [&](const float* W, int row) -> short8 {
        const float* p = W + row*32 + q4*8;
        float4 u0 = *(const float4*)p;
        float4 u1 = *(const float4*)(p + 4);
        S8U t;
        t.u[0] = pk2(u0.x, u0.y); t.u[1] = pk2(u0.z, u0.w);
        t.u[2] = pk2(u1.x, u1.y); t.u[3] = pk2(u1.z, u1.w);
        return t.s;
    };

    const float escale = 0.35355339059327373f * 1.4426950408889634f; // 1/sqrt(8)*log2(e)

    // ---- hoisted per-block state ----
    const short8 wq8 = wrow(Wq, 16*w + l15);
    const short8 wk8 = wrow(Wk, 16*w + l15);
    const short8 wv8 = wrow(Wv, 16*w + l15);
    float4 bq4s = *(const float4*)(bq + 16*w + q4*4);
    bq4s.x *= escale; bq4s.y *= escale; bq4s.z *= escale; bq4s.w *= escale;
    const float4 bk4 = *(const float4*)(bk + 16*w + q4*4);
    const float  bvv = bv[16*w + l15];
    short8 wpb[2];
    wpb[0] = wrow(Wp, l15);
    wpb[1] = wrow(Wp, 16 + l15);
    const float bpv[2] = { bp[l15], bp[16 + l15] };

    // one-time fills (each wave covers everything it reads; benign duplicates)
    {   // klds zero cols 48..55, all 64 rows
        uint4 z; z.x = z.y = z.z = z.w = 0u;
        *(uint4*)&klds[lane][48] = z;
    }
    if (q4 == 0) {   // vbt ones row 32 (V staging never touches row 32)
        uint2 ones; ones.x = 0x3F803F80u; ones.y = 0x3F803F80u;
        *(uint2*)&vbt[32][l15*4] = ones;
    }

#pragma unroll 1
    for (int bi = 0; bi < NBPB; ++bi) {
        const int b = blockIdx.x * NBPB + bi;
        const int aab = aatt[b];

        // allowed(j) == j <= max(i, aab-1); j = (compile-time C) + q4*4
        int cmpv[4];
#pragma unroll
        for (int it = 0; it < 4; ++it) cmpv[it] = max(l15 + 16*it, aab - 1) - q4*4;

        // ---- X fragments: row = tile*16+l15, k = q4*8+e ----
        short8 xa[4];
        const float* xb = x + (size_t)b * 64 * 32;
#pragma unroll
        for (int nt = 0; nt < 4; ++nt) {
            const float* p = xb + (nt*16 + l15)*32 + q4*8;
            float4 u0 = *(const float4*)p;
            float4 u1 = *(const float4*)(p + 4);
            S8U t;
            t.u[0] = pk2(u0.x, u0.y); t.u[1] = pk2(u0.z, u0.w);
            t.u[2] = pk2(u1.x, u1.y); t.u[3] = pk2(u1.z, u1.w);
            xa[nt] = t.s;
        }

        // ---- Q^T (this wave's 16 dims, pre-scaled) -> qlds cols 16w.. ----
#pragma unroll
        for (int nt = 0; nt < 4; ++nt) {
            f32x4 acc = {0.f,0.f,0.f,0.f};
            acc = MFMA(wq8, xa[nt], acc, 0,0,0);
            uint2 w2;
            w2.x = pk2(fmaf(acc[0], escale, bq4s.x), fmaf(acc[1], escale, bq4s.y));
            w2.y = pk2(fmaf(acc[2], escale, bq4s.z), fmaf(acc[3], escale, bq4s.w));
            *(uint2*)&qlds[nt*16 + l15][16*w + q4*4] = w2;
        }
        // ---- K^T (this wave's 16 dims) -> klds cols 16w.. ----
#pragma unroll
        for (int nt = 0; nt < 4; ++nt) {
            f32x4 acc = {0.f,0.f,0.f,0.f};
            acc = MFMA(wk8, xa[nt], acc, 0,0,0);
            uint2 w2;
            w2.x = pk2(acc[0]+bk4.x, acc[1]+bk4.y);
            w2.y = pk2(acc[2]+bk4.z, acc[3]+bk4.w);
            *(uint2*)&klds[nt*16 + l15][16*w + q4*4] = w2;
        }
        // ---- V (this wave's 16 dims) -> vbt rows 16w.., sigma-permuted:
        // j = mt*16+q4*4+r  ->  p = (mt>>1)*32 + q4*8 + (mt&1)*4 + r ----
#pragma unroll
        for (int mt = 0; mt < 4; ++mt) {
            f32x4 acc = {0.f,0.f,0.f,0.f};
            acc = MFMA(xa[mt], wv8, acc, 0,0,0);
            uint2 w2;
            w2.x = pk2(acc[0]+bvv, acc[1]+bvv);
            w2.y = pk2(acc[2]+bvv, acc[3]+bvv);
            *(uint2*)&vbt[16*w + l15][(mt >> 1)*32 + q4*8 + (mt & 1)*4] = w2;
        }
        // (wave reads only own-staged qlds/klds cols + own vbt rows + const
        //  fills -> no staging barrier)

        // ---- head loop (2 heads per wave) ----
#pragma unroll
        for (int hl = 0; hl < 2; ++hl) {
            const int h = 2*w + hl;
            // A-side zero trick: q4==0 lanes read K dims 8h..8h+7,
            // q4>=1 lanes read the zero cols 48..55 -> k>=8 contributes 0.
            const int coff = (q4 == 0) ? 8*h : 48;   // element offset in row

            // Q B-frags: one broadcast b128 per i-tile (no masking needed)
            short8 sqb[4];
#pragma unroll
            for (int it = 0; it < 4; ++it) {
                S8U t; t.v = *(const uint4*)&qlds[it*16 + l15][8*h];
                sqb[it] = t.s;
            }

            // V^T A-frag rows: dims for l15<8, ones row (colsum) for l15>=8
            const int avrow = (l15 < 8) ? (16*w + 8*hl + l15) : 32;

            f32x4 oacch[4];
#pragma unroll
            for (int it = 0; it < 4; ++it) oacch[it] = (f32x4){0.f,0.f,0.f,0.f};

#pragma unroll
            for (int jb = 0; jb < 2; ++jb) {
                S8U ska0, ska1, av;
                ska0.v = *(const uint4*)(&klds[jb*32 + l15][0] + coff);
                ska1.v = *(const uint4*)(&klds[jb*32 + 16 + l15][0] + coff);
                av.v   = *(const uint4*)&vbt[avrow][jb*32 + q4*8];

#pragma unroll
                for (int it = 0; it < 4; ++it) {
                    S8U pb;
                    {   // jt = 0: P j-slots q4*4..+3 -> pb dwords 0,1
                        f32x4 sacc = {0.f,0.f,0.f,0.f};
                        sacc = MFMA(ska0.s, sqb[it], sacc, 0,0,0);
                        float e[4];
#pragma unroll
                        for (int r = 0; r < 4; ++r) {
                            float ee = __builtin_amdgcn_exp2f(sacc[r]);
                            e[r] = (jb*32 + r <= cmpv[it]) ? ee : 0.0f;
                        }
                        pb.u[0] = pk2(e[0], e[1]); pb.u[1] = pk2(e[2], e[3]);
                    }
                    {   // jt = 1: P j-slots 16+q4*4..+3 -> pb dwords 2,3
                        f32x4 sacc = {0.f,0.f,0.f,0.f};
                        sacc = MFMA(ska1.s, sqb[it], sacc, 0,0,0);
                        float e[4];
#pragma unroll
                        for (int r = 0; r < 4; ++r) {
                            float ee = __builtin_amdgcn_exp2f(sacc[r]);
                            e[r] = (jb*32 + 16 + r <= cmpv[it]) ? ee : 0.0f;
                        }
                        pb.u[2] = pk2(e[0], e[1]); pb.u[3] = pk2(e[2], e[3]);
                    }
                    oacch[it] = MFMA(av.s, pb.s, oacch[it], 0,0,0);
                }
            }

            // colsum in C-row 8 (lane 32+l15, reg 0) via the ones row;
            // normalize; O-frags -> qlds cols 8h (after this head's sqb reads)
#pragma unroll
            for (int it = 0; it < 4; ++it) {
                FI s; s.i = BPERM((32 + l15) * 4,
                                  __builtin_bit_cast(int, oacch[it][0]));
                const float inv = __builtin_amdgcn_rcpf(s.f);
                const unsigned o01 = pk2(oacch[it][0]*inv, oacch[it][1]*inv);
                const unsigned o23 = pk2(oacch[it][2]*inv, oacch[it][3]*inv);
                if (q4 < 2) {
                    uint2 ow; ow.x = o01; ow.y = o23;
                    *(uint2*)&qlds[it*16 + l15][8*h + q4*4] = ow;
                }
            }
        }

        // ---- tail: concat-head full-K out-projection ----
        __syncthreads();   // other wave's O-cols (qlds) must be visible

        float* ob = out + (size_t)b * 64 * 32;
#pragma unroll
        for (int u = 0; u < 2; ++u) {       // this wave's i-tiles: 2w, 2w+1
            S8U oa; oa.v = *(const uint4*)&qlds[(2*w + u)*16 + l15][q4*8];
#pragma unroll
            for (int nt = 0; nt < 2; ++nt) {
                f32x4 y = {0.f,0.f,0.f,0.f};
                y = MFMA(oa.s, wpb[nt], y, 0,0,0);
#pragma unroll
                for (int r = 0; r < 4; ++r)
                    ob[((2*w + u)*16 + q4*4 + r)*32 + nt*16 + l15] = y[r] + bpv[nt];
            }
        }

        __syncthreads();   // qlds/klds/vbt reuse by next batch's staging
    }
}

extern "C" void kernel_launch(void* const* d_in, const int* in_sizes, int n_in,
                              void* d_out, int out_size, void* d_ws, size_t ws_size,
                              hipStream_t stream) {
    const float* x  = (const float*)d_in[0];
    const int*   aa = (const int*)d_in[1];
    const float* Wq = (const float*)d_in[2];
    const float* bq = (const float*)d_in[3];
    const float* Wk = (const float*)d_in[4];
    const float* bk = (const float*)d_in[5];
    const float* Wv = (const float*)d_in[6];
    const float* bv = (const float*)d_in[7];
    const float* Wp = (const float*)d_in[8];
    const float* bp = (const float*)d_in[9];
    float* out = (float*)d_out;

    dim3 grid(NB / NBPB), block(128);
    hipLaunchKernelGGL(fused_attn_mfma, grid, block, 0, stream,
                       x, aa, Wq, bq, Wk, bk, Wv, bv, Wp, bp, out);
}

// Round 19
// 50.763 us; speedup vs baseline: 1.3314x; 1.0565x over previous
//
#include <hip/hip_runtime.h>
#include <cstdint>
#include <cstddef>

// Fused prefix-LM self-attention, B=8192, S=64, D=32, H=4, DH=8.
// Block = 128 thr = 2 waves; NBPB=2 batches/block (grid 4096 -> weights
// amortized 2x without R15's occupancy grid-cap). R14 math: bf16 MFMA
// 16x16x32; sigma-permuted V^T (P feeds PV from registers); ones-row
// colsum; concat-head full-K tail. R19: prefix-LM mask as PACKED AND:
// pm[jb][it][k] dwords (prefix masks over bf16 pairs) built ONCE per
// batch and shared by both heads; exp2 runs unconditionally and the
// packed P dwords are ANDed -> deletes 256 cmp+cndmask per wave/batch,
// replaces with 128 build + 64 and.
#define NB 8192
#define NBPB 2

typedef __attribute__((ext_vector_type(8))) short short8;
typedef __attribute__((ext_vector_type(4))) float f32x4;

union S8U { short8 s; unsigned u[4]; uint4 v; };
union FI { float f; int i; unsigned u; };

static __device__ __forceinline__ unsigned pk2(float a, float b) {
    unsigned short ua = __builtin_bit_cast(unsigned short, (__bf16)a);
    unsigned short ub = __builtin_bit_cast(unsigned short, (__bf16)b);
    return (unsigned)ua | ((unsigned)ub << 16);
}

#define MFMA __builtin_amdgcn_mfma_f32_16x16x32_bf16
#define BPERM __builtin_amdgcn_ds_bpermute

__global__ __launch_bounds__(128, 4) void fused_attn_mfma(
    const float* __restrict__ x,
    const int*   __restrict__ aatt,
    const float* __restrict__ Wq, const float* __restrict__ bq,
    const float* __restrict__ Wk, const float* __restrict__ bk,
    const float* __restrict__ Wv, const float* __restrict__ bv,
    const float* __restrict__ Wp, const float* __restrict__ bp,
    float* __restrict__ out)
{
    __shared__ __align__(16) short klds[64][40];   // K[seq][dim]; tail: O[i][dim]
    __shared__ __align__(16) short vbt[33][72];    // V^T[dim][sigma(j)] + ones row

    const int tid  = threadIdx.x;
    const int w    = tid >> 6;          // wave: heads {2w, 2w+1}, dims 16w..16w+15
    const int lane = tid & 63;
    const int q4   = lane >> 4;
    const int l15  = lane & 15;

    const unsigned bmask = (q4 == 0) ? 0xFFFFFFFFu : 0u;

    auto wrow = [&](const float* W, int row) -> short8 {
        const float* p = W + row*32 + q4*8;
        float4 u0 = *(const float4*)p;
        float4 u1 = *(const float4*)(p + 4);
        S8U t;
        t.u[0] = pk2(u0.x, u0.y); t.u[1] = pk2(u0.z, u0.w);
        t.u[2] = pk2(u1.x, u1.y); t.u[3] = pk2(u1.z, u1.w);
        return t.s;
    };

    const float escale = 0.35355339059327373f * 1.4426950408889634f; // 1/sqrt(8)*log2(e)

    // ---- hoisted per-block state ----
    const short8 wq8 = wrow(Wq, 16*w + l15);
    const short8 wk8 = wrow(Wk, 16*w + l15);
    const short8 wv8 = wrow(Wv, 16*w + l15);
    const float4 bq4 = *(const float4*)(bq + 16*w + q4*4);
    const float4 bk4 = *(const float4*)(bk + 16*w + q4*4);
    const float  bvv = bv[16*w + l15];
    short8 wpb[2];
    wpb[0] = wrow(Wp, l15);
    wpb[1] = wrow(Wp, 16 + l15);
    const float bpv[2] = { bp[l15], bp[16 + l15] };

    if (q4 == 0) {   // ones row 32, written once (V staging never touches it)
        uint2 ones; ones.x = 0x3F803F80u; ones.y = 0x3F803F80u;
        *(uint2*)&vbt[32][l15*4] = ones;
    }

    // prefix mask for a bf16 pair (ra, ra+1) with per-lane threshold s = t - ra:
    // s<0 -> 0, s==0 -> keep lo only, s>=1 -> keep both
    auto pairmask = [](int s) -> unsigned {
        unsigned m = (s >= 1) ? 0xFFFFFFFFu : 0x0000FFFFu;
        return (s < 0) ? 0u : m;
    };

#pragma unroll 1
    for (int bi = 0; bi < NBPB; ++bi) {
        const int b = blockIdx.x * NBPB + bi;
        const int aab = aatt[b];

        // cmpv[it]: allowed(j) == jb*32 + jt*16 + r <= cmpv[it]
        int cmpv[4];
#pragma unroll
        for (int it = 0; it < 4; ++it) cmpv[it] = max(l15 + 16*it, aab - 1) - q4*4;

        // packed AND-masks, shared across both heads
        unsigned pm[2][4][4];
#pragma unroll
        for (int jb = 0; jb < 2; ++jb)
#pragma unroll
            for (int it = 0; it < 4; ++it) {
                const int t0 = cmpv[it] - jb*32;
                pm[jb][it][0] = pairmask(t0);        // jt0, pair (0,1)
                pm[jb][it][1] = pairmask(t0 - 2);    // jt0, pair (2,3)
                pm[jb][it][2] = pairmask(t0 - 16);   // jt1, pair (0,1)
                pm[jb][it][3] = pairmask(t0 - 18);   // jt1, pair (2,3)
            }

        // ---- X fragments ----
        short8 xa[4];
        const float* xb = x + (size_t)b * 64 * 32;
#pragma unroll
        for (int nt = 0; nt < 4; ++nt) {
            const float* p = xb + (nt*16 + l15)*32 + q4*8;
            float4 u0 = *(const float4*)p;
            float4 u1 = *(const float4*)(p + 4);
            S8U t;
            t.u[0] = pk2(u0.x, u0.y); t.u[1] = pk2(u0.z, u0.w);
            t.u[2] = pk2(u1.x, u1.y); t.u[3] = pk2(u1.z, u1.w);
            xa[nt] = t.s;
        }

        // ---- Q^T -> registers (packed, pre-scaled) ----
        unsigned qpk01[4], qpk23[4];
#pragma unroll
        for (int nt = 0; nt < 4; ++nt) {
            f32x4 acc = {0.f,0.f,0.f,0.f};
            acc = MFMA(wq8, xa[nt], acc, 0,0,0);
            qpk01[nt] = pk2((acc[0]+bq4.x)*escale, (acc[1]+bq4.y)*escale);
            qpk23[nt] = pk2((acc[2]+bq4.z)*escale, (acc[3]+bq4.w)*escale);
        }
        // ---- K^T -> klds cols 16w.. ----
#pragma unroll
        for (int nt = 0; nt < 4; ++nt) {
            f32x4 acc = {0.f,0.f,0.f,0.f};
            acc = MFMA(wk8, xa[nt], acc, 0,0,0);
            uint2 w2;
            w2.x = pk2(acc[0]+bk4.x, acc[1]+bk4.y);
            w2.y = pk2(acc[2]+bk4.z, acc[3]+bk4.w);
            *(uint2*)&klds[nt*16 + l15][16*w + q4*4] = w2;
        }
        // ---- V -> vbt rows 16w.., sigma-permuted columns ----
#pragma unroll
        for (int mt = 0; mt < 4; ++mt) {
            f32x4 acc = {0.f,0.f,0.f,0.f};
            acc = MFMA(xa[mt], wv8, acc, 0,0,0);
            uint2 w2;
            w2.x = pk2(acc[0]+bvv, acc[1]+bvv);
            w2.y = pk2(acc[2]+bvv, acc[3]+bvv);
            *(uint2*)&vbt[16*w + l15][(mt >> 1)*32 + q4*8 + (mt & 1)*4] = w2;
        }

        // ---- head loop (2 heads per wave); P stays in registers ----
#pragma unroll
        for (int hl = 0; hl < 2; ++hl) {
            const int idxA = (32*hl + l15) * 4;    // lane (q4=2hl,   l15)
            const int idxB = idxA + 64;            // lane (q4=2hl+1, l15)

            // Q B-frags: zero k>=8 via bmask
            short8 sqb[4];
#pragma unroll
            for (int it = 0; it < 4; ++it) {
                S8U t;
                t.u[0] = (unsigned)BPERM(idxA, (int)qpk01[it]) & bmask;
                t.u[1] = (unsigned)BPERM(idxA, (int)qpk23[it]) & bmask;
                t.u[2] = (unsigned)BPERM(idxB, (int)qpk01[it]) & bmask;
                t.u[3] = (unsigned)BPERM(idxB, (int)qpk23[it]) & bmask;
                sqb[it] = t.s;
            }

            // V^T A-frag rows: dims for l15<8, ones row (colsum) for l15>=8
            const int avrow = (l15 < 8) ? (16*w + 8*hl + l15) : 32;

            f32x4 oacch[4];
#pragma unroll
            for (int it = 0; it < 4; ++it) oacch[it] = (f32x4){0.f,0.f,0.f,0.f};

#pragma unroll
            for (int jb = 0; jb < 2; ++jb) {
                S8U ska0, ska1, av;
                ska0.v = *(const uint4*)&klds[jb*32 + l15][16*w + 8*hl];
                ska1.v = *(const uint4*)&klds[jb*32 + 16 + l15][16*w + 8*hl];
                av.v   = *(const uint4*)&vbt[avrow][jb*32 + q4*8];

#pragma unroll
                for (int it = 0; it < 4; ++it) {
                    S8U pb;
                    {   // jt = 0
                        f32x4 sacc = {0.f,0.f,0.f,0.f};
                        sacc = MFMA(ska0.s, sqb[it], sacc, 0,0,0);
                        pb.u[0] = pk2(__builtin_amdgcn_exp2f(sacc[0]),
                                      __builtin_amdgcn_exp2f(sacc[1])) & pm[jb][it][0];
                        pb.u[1] = pk2(__builtin_amdgcn_exp2f(sacc[2]),
                                      __builtin_amdgcn_exp2f(sacc[3])) & pm[jb][it][1];
                    }
                    {   // jt = 1
                        f32x4 sacc = {0.f,0.f,0.f,0.f};
                        sacc = MFMA(ska1.s, sqb[it], sacc, 0,0,0);
                        pb.u[2] = pk2(__builtin_amdgcn_exp2f(sacc[0]),
                                      __builtin_amdgcn_exp2f(sacc[1])) & pm[jb][it][2];
                        pb.u[3] = pk2(__builtin_amdgcn_exp2f(sacc[2]),
                                      __builtin_amdgcn_exp2f(sacc[3])) & pm[jb][it][3];
                    }
                    oacch[it] = MFMA(av.s, pb.s, oacch[it], 0,0,0);
                }
            }

            // colsum in C-row 8 (lane 32+l15, reg 0) via ones row; normalize
#pragma unroll
            for (int it = 0; it < 4; ++it) {
                FI s; s.i = BPERM((32 + l15) * 4,
                                  __builtin_bit_cast(int, oacch[it][0]));
                const float inv = __builtin_amdgcn_rcpf(s.f);
                const unsigned o01 = pk2(oacch[it][0]*inv, oacch[it][1]*inv);
                const unsigned o23 = pk2(oacch[it][2]*inv, oacch[it][3]*inv);
                if (q4 < 2) {
                    uint2 ow; ow.x = o01; ow.y = o23;
                    *(uint2*)&klds[it*16 + l15][(2*w + hl)*8 + q4*4] = ow;
                }
            }
        }

        // ---- tail: concat-head full-K out-projection ----
        __syncthreads();   // other wave's O-cols must be visible

        float* ob = out + (size_t)b * 64 * 32;
#pragma unroll
        for (int u = 0; u < 2; ++u) {       // this wave's i-tiles: 2w, 2w+1
            S8U oa; oa.v = *(const uint4*)&klds[(2*w + u)*16 + l15][q4*8];
#pragma unroll
            for (int nt = 0; nt < 2; ++nt) {
                f32x4 y = {0.f,0.f,0.f,0.f};
                y = MFMA(oa.s, wpb[nt], y, 0,0,0);
#pragma unroll
                for (int r = 0; r < 4; ++r)
                    ob[((2*w + u)*16 + q4*4 + r)*32 + nt*16 + l15] = y[r] + bpv[nt];
            }
        }

        __syncthreads();   // klds/vbt reuse by next batch's staging
    }
}

extern "C" void kernel_launch(void* const* d_in, const int* in_sizes, int n_in,
                              void* d_out, int out_size, void* d_ws, size_t ws_size,
                              hipStream_t stream) {
    const float* x  = (const float*)d_in[0];
    const int*   aa = (const int*)d_in[1];
    const float* Wq = (const float*)d_in[2];
    const float* bq = (const float*)d_in[3];
    const float* Wk = (const float*)d_in[4];
    const float* bk = (const float*)d_in[5];
    const float* Wv = (const float*)d_in[6];
    const float* bv = (const float*)d_in[7];
    const float* Wp = (const float*)d_in[8];
    const float* bp = (const float*)d_in[9];
    float* out = (float*)d_out;

    dim3 grid(NB / NBPB), block(128);
    hipLaunchKernelGGL(fused_attn_mfma, grid, block, 0, stream,
                       x, aa, Wq, bq, Wk, bk, Wv, bv, Wp, bp, out);
}